// Round 1
// baseline (1776.753 us; speedup 1.0000x reference)
//
#include <hip/hip_runtime.h>

#define RR 32
#define R3 32768           // 32^3
#define NPTS 65536
#define NCH 64
#define NB 8

// d_ws layout:
//   [0, 192):   double sums[B*3]   (mean accumulators)
//   [192, 224): uint   maxbits[B]  (max squared-norm, float bits)
//   [1024, 1024 + NB*R3*4): float counts[B][R3]

__global__ void mean_kernel(const float* __restrict__ coords, double* __restrict__ sums) {
    int b = blockIdx.y;
    int tid = blockIdx.x * blockDim.x + threadIdx.x;
    int stride = gridDim.x * blockDim.x;
    const float* cb = coords + (size_t)b * 3 * NPTS;
    double sx = 0.0, sy = 0.0, sz = 0.0;
    for (int n = tid; n < NPTS; n += stride) {
        sx += cb[n];
        sy += cb[NPTS + n];
        sz += cb[2 * NPTS + n];
    }
    // wave(64) butterfly reduce
    for (int off = 32; off > 0; off >>= 1) {
        sx += __shfl_down(sx, off);
        sy += __shfl_down(sy, off);
        sz += __shfl_down(sz, off);
    }
    if ((threadIdx.x & 63) == 0) {
        atomicAdd(&sums[b * 3 + 0], sx);
        atomicAdd(&sums[b * 3 + 1], sy);
        atomicAdd(&sums[b * 3 + 2], sz);
    }
}

__global__ void maxnorm_kernel(const float* __restrict__ coords,
                               const double* __restrict__ sums,
                               unsigned* __restrict__ maxbits) {
    int b = blockIdx.y;
    float mx = (float)(sums[b * 3 + 0] * (1.0 / NPTS));
    float my = (float)(sums[b * 3 + 1] * (1.0 / NPTS));
    float mz = (float)(sums[b * 3 + 2] * (1.0 / NPTS));
    int tid = blockIdx.x * blockDim.x + threadIdx.x;
    int stride = gridDim.x * blockDim.x;
    const float* cb = coords + (size_t)b * 3 * NPTS;
    float m = 0.0f;
    for (int n = tid; n < NPTS; n += stride) {
        float dx = cb[n] - mx;
        float dy = cb[NPTS + n] - my;
        float dz = cb[2 * NPTS + n] - mz;
        float d2 = dx * dx + dy * dy + dz * dz;
        m = fmaxf(m, d2);
    }
    for (int off = 32; off > 0; off >>= 1) {
        m = fmaxf(m, __shfl_down(m, off));
    }
    if ((threadIdx.x & 63) == 0) {
        atomicMax(&maxbits[b], __float_as_uint(m));  // m >= 0: uint order == float order
    }
}

__global__ void scatter_kernel(const float* __restrict__ feats,
                               const float* __restrict__ coords,
                               const double* __restrict__ sums,
                               const unsigned* __restrict__ maxbits,
                               float* __restrict__ voxsum,
                               float* __restrict__ ncout,
                               float* __restrict__ cnt) {
    int b = blockIdx.y;
    int n = blockIdx.x * blockDim.x + threadIdx.x;
    float mx = (float)(sums[b * 3 + 0] * (1.0 / NPTS));
    float my = (float)(sums[b * 3 + 1] * (1.0 / NPTS));
    float mz = (float)(sums[b * 3 + 2] * (1.0 / NPTS));
    float denom = 2.0f * sqrtf(__uint_as_float(maxbits[b]));  // EPS = 0

    const float* cb = coords + (size_t)b * 3 * NPTS;
    float dx = cb[n] - mx;
    float dy = cb[NPTS + n] - my;
    float dz = cb[2 * NPTS + n] - mz;

    float qx = fminf(fmaxf((dx / denom + 0.5f) * 32.0f, 0.0f), 31.0f);
    float qy = fminf(fmaxf((dy / denom + 0.5f) * 32.0f, 0.0f), 31.0f);
    float qz = fminf(fmaxf((dz / denom + 0.5f) * 32.0f, 0.0f), 31.0f);

    // nc output [B,3,N]
    float* nb_ = ncout + (size_t)b * 3 * NPTS;
    nb_[n] = qx;
    nb_[NPTS + n] = qy;
    nb_[2 * NPTS + n] = qz;

    int vx = (int)rintf(qx);   // nearest-even == jnp.round
    int vy = (int)rintf(qy);
    int vz = (int)rintf(qz);
    int flat = (vx * RR + vy) * RR + vz;

    atomicAdd(&cnt[b * R3 + flat], 1.0f);

    const float* fb = feats + (size_t)b * NCH * NPTS + n;
    float* ob = voxsum + (size_t)b * NCH * R3 + flat;
#pragma unroll 8
    for (int c = 0; c < NCH; c++) {
        atomicAdd(ob + (size_t)c * R3, fb[(size_t)c * NPTS]);
    }
}

__global__ void normalize_kernel(float* __restrict__ voxsum, const float* __restrict__ cnt) {
    int i = blockIdx.x * blockDim.x + threadIdx.x;   // over NB*R3
    int b = i >> 15;
    int v = i & (R3 - 1);
    float c = cnt[i];
    float inv = 1.0f / fmaxf(c, 1.0f);
    float* ob = voxsum + ((size_t)b * NCH) * R3 + v;
#pragma unroll 8
    for (int c2 = 0; c2 < NCH; c2++) {
        ob[(size_t)c2 * R3] *= inv;
    }
}

extern "C" void kernel_launch(void* const* d_in, const int* in_sizes, int n_in,
                              void* d_out, int out_size, void* d_ws, size_t ws_size,
                              hipStream_t stream) {
    const float* feats  = (const float*)d_in[0];   // [8,64,65536]
    const float* coords = (const float*)d_in[1];   // [8,3,65536]
    float* out = (float*)d_out;
    float* voxsum = out;                                   // [8,64,32768]
    float* ncout  = out + (size_t)NB * NCH * R3;           // [8,3,65536]

    double*   sums    = (double*)d_ws;
    unsigned* maxbits = (unsigned*)((char*)d_ws + 192);
    float*    cnt     = (float*)((char*)d_ws + 1024);

    // d_ws / d_out are poisoned 0xAA before every call — zero what we accumulate into.
    hipMemsetAsync(d_ws, 0, 1024 + (size_t)NB * R3 * sizeof(float), stream);
    hipMemsetAsync(voxsum, 0, (size_t)NB * NCH * R3 * sizeof(float), stream);

    mean_kernel   <<<dim3(32, NB), 256, 0, stream>>>(coords, sums);
    maxnorm_kernel<<<dim3(32, NB), 256, 0, stream>>>(coords, sums, maxbits);
    scatter_kernel<<<dim3(NPTS / 256, NB), 256, 0, stream>>>(feats, coords, sums, maxbits,
                                                             voxsum, ncout, cnt);
    normalize_kernel<<<(NB * R3) / 256, 256, 0, stream>>>(voxsum, cnt);
}

// Round 2
// 399.154 us; speedup vs baseline: 4.4513x; 4.4513x over previous
//
#include <hip/hip_runtime.h>

#define RR 32
#define R3 32768           // 32^3
#define NPTS 65536
#define NCH 64
#define NB 8

// d_ws layout (fast path):
//   [0, 192):    double sums[B*3]
//   [192, 224):  uint   maxbits[B]
//   [4096, 4096+1MB):        float cnt[B][R3]
//   [1052672, 1052672+64MB): float ws_vox[B][R3][C]   (voxel-major accumulator)

__global__ void mean_kernel(const float* __restrict__ coords, double* __restrict__ sums) {
    int b = blockIdx.y;
    int tid = blockIdx.x * blockDim.x + threadIdx.x;
    int stride = gridDim.x * blockDim.x;
    const float* cb = coords + (size_t)b * 3 * NPTS;
    double sx = 0.0, sy = 0.0, sz = 0.0;
    for (int n = tid; n < NPTS; n += stride) {
        sx += cb[n];
        sy += cb[NPTS + n];
        sz += cb[2 * NPTS + n];
    }
    for (int off = 32; off > 0; off >>= 1) {
        sx += __shfl_down(sx, off);
        sy += __shfl_down(sy, off);
        sz += __shfl_down(sz, off);
    }
    if ((threadIdx.x & 63) == 0) {
        atomicAdd(&sums[b * 3 + 0], sx);
        atomicAdd(&sums[b * 3 + 1], sy);
        atomicAdd(&sums[b * 3 + 2], sz);
    }
}

__global__ void maxnorm_kernel(const float* __restrict__ coords,
                               const double* __restrict__ sums,
                               unsigned* __restrict__ maxbits) {
    int b = blockIdx.y;
    float mx = (float)(sums[b * 3 + 0] * (1.0 / NPTS));
    float my = (float)(sums[b * 3 + 1] * (1.0 / NPTS));
    float mz = (float)(sums[b * 3 + 2] * (1.0 / NPTS));
    int tid = blockIdx.x * blockDim.x + threadIdx.x;
    int stride = gridDim.x * blockDim.x;
    const float* cb = coords + (size_t)b * 3 * NPTS;
    float m = 0.0f;
    for (int n = tid; n < NPTS; n += stride) {
        float dx = cb[n] - mx;
        float dy = cb[NPTS + n] - my;
        float dz = cb[2 * NPTS + n] - mz;
        m = fmaxf(m, dx * dx + dy * dy + dz * dz);
    }
    for (int off = 32; off > 0; off >>= 1) {
        m = fmaxf(m, __shfl_down(m, off));
    }
    if ((threadIdx.x & 63) == 0) {
        atomicMax(&maxbits[b], __float_as_uint(m));  // m >= 0: uint order == float order
    }
}

// ---------- fast path: voxel-major accumulation ----------

// Block = 256 threads handles 64 points (all 64 channels).
// LDS-transposes the 64x64 feature tile so each wave does one fully
// coalesced 64-lane atomicAdd (256 contiguous bytes) per point.
__global__ void scatter_vm_kernel(const float* __restrict__ feats,
                                  const float* __restrict__ coords,
                                  const double* __restrict__ sums,
                                  const unsigned* __restrict__ maxbits,
                                  float* __restrict__ ws_vox,   // [B][R3][C]
                                  float* __restrict__ ncout,
                                  float* __restrict__ cnt) {
    __shared__ float tile[64][65];   // [point][channel], padded
    __shared__ int   sflat[64];

    int b  = blockIdx.y;
    int n0 = blockIdx.x * 64;
    int t  = threadIdx.x;

    // phase 0: threads 0..63 compute nc + voxel id for the 64 points
    if (t < 64) {
        int n = n0 + t;
        float mx = (float)(sums[b * 3 + 0] * (1.0 / NPTS));
        float my = (float)(sums[b * 3 + 1] * (1.0 / NPTS));
        float mz = (float)(sums[b * 3 + 2] * (1.0 / NPTS));
        float denom = 2.0f * sqrtf(__uint_as_float(maxbits[b]));  // EPS = 0
        const float* cb = coords + (size_t)b * 3 * NPTS;
        float dx = cb[n] - mx;
        float dy = cb[NPTS + n] - my;
        float dz = cb[2 * NPTS + n] - mz;
        float qx = fminf(fmaxf((dx / denom + 0.5f) * 32.0f, 0.0f), 31.0f);
        float qy = fminf(fmaxf((dy / denom + 0.5f) * 32.0f, 0.0f), 31.0f);
        float qz = fminf(fmaxf((dz / denom + 0.5f) * 32.0f, 0.0f), 31.0f);
        float* nb_ = ncout + (size_t)b * 3 * NPTS;
        nb_[n] = qx;
        nb_[NPTS + n] = qy;
        nb_[2 * NPTS + n] = qz;
        int flat = ((int)rintf(qx) * RR + (int)rintf(qy)) * RR + (int)rintf(qz);
        sflat[t] = flat;
        atomicAdd(&cnt[b * R3 + flat], 1.0f);
    }

    // phase 1: coalesced load of 64 channels x 64 points, transposed into LDS
    const float* fb = feats + (size_t)b * NCH * NPTS + n0;
    int i = t & 63;          // point
    int c0 = t >> 6;         // 0..3
#pragma unroll
    for (int iter = 0; iter < 16; iter++) {
        int c = iter * 4 + c0;
        tile[i][c] = fb[(size_t)c * NPTS + i];
    }
    __syncthreads();

    // phase 2: each wave handles 16 points; 64-lane coalesced atomic per point
    int wave = t >> 6;
    int lane = t & 63;
#pragma unroll
    for (int k = 0; k < 16; k++) {
        int p = wave * 16 + k;
        float v = tile[p][lane];
        size_t base = ((size_t)b * R3 + sflat[p]) * NCH;
        atomicAdd(&ws_vox[base + lane], v);
    }
}

// Divide by count and transpose [B][R3][C] -> [B][C][R3] into d_out.
__global__ void normalize_t_kernel(const float* __restrict__ ws_vox,
                                   const float* __restrict__ cnt,
                                   float* __restrict__ voxout) {
    __shared__ float tile[64][65];   // [channel][voxel]
    __shared__ float cinv[64];

    int b  = blockIdx.y;
    int v0 = blockIdx.x * 64;
    int t  = threadIdx.x;

    if (t < 64) {
        float c = cnt[b * R3 + v0 + t];
        cinv[t] = 1.0f / fmaxf(c, 1.0f);
    }

    // load: consecutive threads -> consecutive channels (coalesced)
    const float* src = ws_vox + ((size_t)b * R3 + v0) * NCH;
    int c = t & 63;
    int vi0 = t >> 6;
#pragma unroll
    for (int iter = 0; iter < 16; iter++) {
        int vi = iter * 4 + vi0;
        tile[c][vi] = src[(size_t)vi * NCH + c];
    }
    __syncthreads();

    // store: consecutive threads -> consecutive voxels (coalesced)
    float* dst = voxout + (size_t)b * NCH * R3 + v0;
    int vi = t & 63;
    int cc0 = t >> 6;
#pragma unroll
    for (int iter = 0; iter < 16; iter++) {
        int cc = iter * 4 + cc0;
        dst[(size_t)cc * R3 + vi] = tile[cc][vi] * cinv[vi];
    }
}

// ---------- fallback path (round-1, channel-major atomics) ----------

__global__ void scatter_kernel(const float* __restrict__ feats,
                               const float* __restrict__ coords,
                               const double* __restrict__ sums,
                               const unsigned* __restrict__ maxbits,
                               float* __restrict__ voxsum,
                               float* __restrict__ ncout,
                               float* __restrict__ cnt) {
    int b = blockIdx.y;
    int n = blockIdx.x * blockDim.x + threadIdx.x;
    float mx = (float)(sums[b * 3 + 0] * (1.0 / NPTS));
    float my = (float)(sums[b * 3 + 1] * (1.0 / NPTS));
    float mz = (float)(sums[b * 3 + 2] * (1.0 / NPTS));
    float denom = 2.0f * sqrtf(__uint_as_float(maxbits[b]));
    const float* cb = coords + (size_t)b * 3 * NPTS;
    float dx = cb[n] - mx;
    float dy = cb[NPTS + n] - my;
    float dz = cb[2 * NPTS + n] - mz;
    float qx = fminf(fmaxf((dx / denom + 0.5f) * 32.0f, 0.0f), 31.0f);
    float qy = fminf(fmaxf((dy / denom + 0.5f) * 32.0f, 0.0f), 31.0f);
    float qz = fminf(fmaxf((dz / denom + 0.5f) * 32.0f, 0.0f), 31.0f);
    float* nb_ = ncout + (size_t)b * 3 * NPTS;
    nb_[n] = qx;
    nb_[NPTS + n] = qy;
    nb_[2 * NPTS + n] = qz;
    int flat = ((int)rintf(qx) * RR + (int)rintf(qy)) * RR + (int)rintf(qz);
    atomicAdd(&cnt[b * R3 + flat], 1.0f);
    const float* fb = feats + (size_t)b * NCH * NPTS + n;
    float* ob = voxsum + (size_t)b * NCH * R3 + flat;
#pragma unroll 8
    for (int c = 0; c < NCH; c++) {
        atomicAdd(ob + (size_t)c * R3, fb[(size_t)c * NPTS]);
    }
}

__global__ void normalize_kernel(float* __restrict__ voxsum, const float* __restrict__ cnt) {
    int i = blockIdx.x * blockDim.x + threadIdx.x;
    int b = i >> 15;
    int v = i & (R3 - 1);
    float inv = 1.0f / fmaxf(cnt[i], 1.0f);
    float* ob = voxsum + ((size_t)b * NCH) * R3 + v;
#pragma unroll 8
    for (int c2 = 0; c2 < NCH; c2++) {
        ob[(size_t)c2 * R3] *= inv;
    }
}

extern "C" void kernel_launch(void* const* d_in, const int* in_sizes, int n_in,
                              void* d_out, int out_size, void* d_ws, size_t ws_size,
                              hipStream_t stream) {
    const float* feats  = (const float*)d_in[0];   // [8,64,65536]
    const float* coords = (const float*)d_in[1];   // [8,3,65536]
    float* out = (float*)d_out;
    float* voxout = out;                                   // [8,64,32768]
    float* ncout  = out + (size_t)NB * NCH * R3;           // [8,3,65536]

    double*   sums    = (double*)d_ws;
    unsigned* maxbits = (unsigned*)((char*)d_ws + 192);
    const size_t off_cnt = 4096;
    const size_t cnt_bytes = (size_t)NB * R3 * sizeof(float);          // 1 MB
    const size_t off_vox = off_cnt + cnt_bytes;                        // 1052672
    const size_t vox_bytes = (size_t)NB * R3 * NCH * sizeof(float);    // 64 MB
    float* cnt    = (float*)((char*)d_ws + off_cnt);
    float* ws_vox = (float*)((char*)d_ws + off_vox);

    mean_kernel   <<<dim3(32, NB), 256, 0, stream>>>(coords, sums);
    // NOTE: mean/maxnorm only read sums/maxbits regions; memset them before use.

    if (ws_size >= off_vox + vox_bytes) {
        // fast path: voxel-major accumulation in d_ws
        hipMemsetAsync((char*)d_ws + 192, 0, 32, stream);                 // maxbits
        hipMemsetAsync(d_ws, 0, 192, stream);                              // sums (re-zero ok: done below pre-mean? see order note)
        hipMemsetAsync((char*)d_ws + off_cnt, 0, cnt_bytes, stream);       // cnt
        hipMemsetAsync((char*)d_ws + off_vox, 0, vox_bytes, stream);       // accumulator
        // sums was poisoned before mean_kernel ran above — must redo mean after zeroing.
        mean_kernel   <<<dim3(32, NB), 256, 0, stream>>>(coords, sums);
        maxnorm_kernel<<<dim3(32, NB), 256, 0, stream>>>(coords, sums, maxbits);
        scatter_vm_kernel<<<dim3(NPTS / 64, NB), 256, 0, stream>>>(
            feats, coords, sums, maxbits, ws_vox, ncout, cnt);
        normalize_t_kernel<<<dim3(R3 / 64, NB), 256, 0, stream>>>(ws_vox, cnt, voxout);
    } else {
        // fallback: round-1 path (channel-major atomics into d_out)
        hipMemsetAsync(d_ws, 0, off_cnt + cnt_bytes, stream);
        hipMemsetAsync(voxout, 0, (size_t)NB * NCH * R3 * sizeof(float), stream);
        mean_kernel   <<<dim3(32, NB), 256, 0, stream>>>(coords, sums);
        maxnorm_kernel<<<dim3(32, NB), 256, 0, stream>>>(coords, sums, maxbits);
        scatter_kernel<<<dim3(NPTS / 256, NB), 256, 0, stream>>>(feats, coords, sums, maxbits,
                                                                 voxout, ncout, cnt);
        normalize_kernel<<<(NB * R3) / 256, 256, 0, stream>>>(voxout, cnt);
    }
}